// Round 2
// baseline (456.222 us; speedup 1.0000x reference)
//
#include <hip/hip_runtime.h>
#include <math.h>

// EMA scan: y[b,0,:] = x[b,0,:]; y[b,t,:] = a*x[b,t,:] + (1-a)*y[b,t-1,:]
// a = sigmoid(raw) per channel. x,y: (16, 4096, 1024) fp32, C contiguous.
//
// v2 design (from r1 post-mortem: barrier vmcnt(0) drain + 4B/lane killed BW):
//  - float4 along C: each thread owns 4 channels (16 B/lane loads/stores).
//  - Block = 256 thr = (32 rows x 8 cols) handles (b, 32 channels), full T.
//    Grid = (1024/32=32, 16) = 512 blocks -> 2 blocks/CU for barrier overlap.
//  - Tile = 256 timesteps (32 row-subchunks x 8 t/thread), 16 tiles.
//  - Linear-recurrence compose: zero-init local scan -> per-row carry in LDS
//    -> every thread walks 32 carries with per-channel d^8 -> fixup + store.
//  - ONE raw s_barrier per tile, preceded only by s_waitcnt lgkmcnt(0).
//    NO vmcnt drain anywhere: next tile's global loads are issued BEFORE the
//    barrier into a register double-buffer and stay in flight across it;
//    stores also never drain. Carry LDS is parity double-buffered (a wave is
//    at most 1 tile ahead, so buffer reuse is barrier-protected).

#define B_DIM  16
#define T_DIM  4096
#define C_DIM  1024
#define CG     32                 // channels per block
#define COLS   8                  // CG/4 float4 columns
#define NROW   32                 // t-subchunks per tile (= rows of threads)
#define LSUB   8                  // timesteps per thread per tile
#define TILE_T (NROW * LSUB)      // 256
#define NTILES (T_DIM / TILE_T)   // 16
#define TSTR   (C_DIM / 4)        // float4 stride between timesteps

__device__ __forceinline__ float4 f4mul(float4 a, float4 b) {
    float4 r; r.x = a.x*b.x; r.y = a.y*b.y; r.z = a.z*b.z; r.w = a.w*b.w; return r;
}
__device__ __forceinline__ float4 f4fma(float4 a, float4 b, float4 c) {
    float4 r;
    r.x = fmaf(a.x, b.x, c.x); r.y = fmaf(a.y, b.y, c.y);
    r.z = fmaf(a.z, b.z, c.z); r.w = fmaf(a.w, b.w, c.w); return r;
}

__global__ __launch_bounds__(256, 2)
void ema_scan_kernel(const float* __restrict__ x,
                     const float* __restrict__ raw,
                     float* __restrict__ y) {
    __shared__ float4 carry[2][NROW][COLS];

    const int tid = threadIdx.x;
    const int col = tid & (COLS - 1);
    const int row = tid >> 3;
    const int cg  = blockIdx.x;
    const int b   = blockIdx.y;
    const int c0  = cg * CG + col * 4;

    // per-channel coefficients (x4)
    const float4 rv = *reinterpret_cast<const float4*>(raw + c0);
    float4 a, d, d8;
    a.x = 1.0f / (1.0f + expf(-rv.x));
    a.y = 1.0f / (1.0f + expf(-rv.y));
    a.z = 1.0f / (1.0f + expf(-rv.z));
    a.w = 1.0f / (1.0f + expf(-rv.w));
    d.x = 1.0f - a.x; d.y = 1.0f - a.y; d.z = 1.0f - a.z; d.w = 1.0f - a.w;
    float4 d2 = f4mul(d, d), d4 = f4mul(d2, d2);
    d8 = f4mul(d4, d4);

    const size_t chanBase = ((size_t)b * T_DIM) * C_DIM + (size_t)c0;
    const float4* xb = reinterpret_cast<const float4*>(x + chanBase);
    float4*       yb = reinterpret_cast<float4*>(y + chanBase);

    float4 run = {0.f, 0.f, 0.f, 0.f};
    float4 xvA[LSUB], xvB[LSUB], yl[LSUB];

#define LOADT(XV, tt) {                                                        \
    const float4* p = xb + (size_t)((tt) * TILE_T + row * LSUB) * TSTR;        \
    _Pragma("unroll")                                                          \
    for (int i = 0; i < LSUB; ++i) XV[i] = p[(size_t)i * TSTR]; }

#define BODY(XC, XN, tt, pb, doload) {                                         \
    /* 1) zero-init local scan over this thread's 8 timesteps */               \
    float4 s;                                                                  \
    if ((tt) == 0 && row == 0) {                                               \
        s = XC[0]; yl[0] = s;   /* global t=0: y0 = x0 exactly */              \
        _Pragma("unroll")                                                      \
        for (int i = 1; i < LSUB; ++i) { s = f4fma(d, s, f4mul(a, XC[i])); yl[i] = s; } \
    } else {                                                                   \
        s.x = s.y = s.z = s.w = 0.f;                                           \
        _Pragma("unroll")                                                      \
        for (int i = 0; i < LSUB; ++i) { s = f4fma(d, s, f4mul(a, XC[i])); yl[i] = s; } \
    }                                                                          \
    /* 2) publish per-row carry */                                             \
    carry[pb][row][col] = s;                                                   \
    /* 3) prefetch next tile BEFORE the barrier (stays in flight across it) */ \
    if (doload) LOADT(XN, (tt) + 1);                                           \
    /* 4) raw barrier: only LDS visibility needed -> lgkmcnt(0), NO vmcnt */   \
    asm volatile("s_waitcnt lgkmcnt(0)" ::: "memory");                         \
    __builtin_amdgcn_s_barrier();                                              \
    asm volatile("" ::: "memory");                                             \
    /* 5) compose carries: carry_{j+1} = local_j + d^8 * carry_j */            \
    float4 acc = run;                                                          \
    float4 cin = {0.f, 0.f, 0.f, 0.f};                                         \
    _Pragma("unroll 8")                                                        \
    for (int j = 0; j < NROW; ++j) {                                           \
        float4 cj = carry[pb][j][col];                                         \
        if (j == row) cin = acc;                                               \
        acc = f4fma(d8, acc, cj);                                              \
    }                                                                          \
    run = acc;                                                                 \
    /* 6) fixup + store: y_t = y_local + d^(i+1) * carry_in */                 \
    float4* q = yb + (size_t)((tt) * TILE_T + row * LSUB) * TSTR;              \
    float4 f = d;                                                              \
    _Pragma("unroll")                                                          \
    for (int i = 0; i < LSUB; ++i) {                                           \
        q[(size_t)i * TSTR] = f4fma(f, cin, yl[i]);                            \
        f = f4mul(f, d);                                                       \
    } }

    LOADT(xvA, 0);
    for (int tp = 0; tp < NTILES; tp += 2) {
        BODY(xvA, xvB, tp,     0, true);
        BODY(xvB, xvA, tp + 1, 1, (tp + 2 < NTILES));
    }
#undef LOADT
#undef BODY
}

extern "C" void kernel_launch(void* const* d_in, const int* in_sizes, int n_in,
                              void* d_out, int out_size, void* d_ws, size_t ws_size,
                              hipStream_t stream) {
    const float* x   = (const float*)d_in[0];
    const float* raw = (const float*)d_in[1];
    float* y = (float*)d_out;

    dim3 grid(C_DIM / CG, B_DIM);   // (32 channel-groups, 16 batches) = 512 blocks
    dim3 block(NROW * COLS);        // 256 threads = 4 waves
    ema_scan_kernel<<<grid, block, 0, stream>>>(x, raw, y);
}